// Round 3
// baseline (438.837 us; speedup 1.0000x reference)
//
#include <hip/hip_runtime.h>

// NGNNConv: out[i,j,:] = m[i,j] * [ (sum_{e: erow[e]=j} m[i,ecol[e]] * X[i,ecol[e],:]) @ W + b*cnt ]
// N=1024, E=8192, IND=OUTD=32, fp32.
//
// R3: block-per-i, but (a) only MASKED X rows staged in LDS (compacted, cap 560
// + global fallback) -> 75 KB LDS -> 2 blocks/CU (full 32-wave occupancy, phase
// overlap across blocks); (b) j's compacted by mask in degree-sorted order
// (jorder precomputed in CSR build) -> dense compute waves + uniform edge loops;
// zero-mask j's handled by fast store-zeros waves.

#define NN   1024
#define IND  32
#define OUTD 32
#define CAP  560     // max compacted rows held in LDS (560*128B = 70 KB)

// ---------------- CSR build ----------------
__global__ __launch_bounds__(1024) void k_zero(int* __restrict__ p, int n) {
    const int t = blockIdx.x * 1024 + threadIdx.x;
    if (t < n) p[t] = 0;
}

__global__ __launch_bounds__(1024) void k_count(const int* __restrict__ erow,
                                                int* __restrict__ cnt, int n_edges) {
    const int e = blockIdx.x * 1024 + threadIdx.x;
    if (e < n_edges) atomicAdd(&cnt[erow[e]], 1);
}

// scan degrees -> row_ptr/fill; also counting-sort j's by degree -> jorder
__global__ __launch_bounds__(1024) void k_scan_sort(const int* __restrict__ cnt,
                                                    int* __restrict__ row_ptr,
                                                    int* __restrict__ fill,
                                                    int* __restrict__ jorder) {
    __shared__ int sb[NN];
    __shared__ int hist[64];
    __shared__ int hoff[64];
    const int t = threadIdx.x;
    const int v = cnt[t];
    sb[t] = v;
    if (t < 64) hist[t] = 0;
    __syncthreads();
    #pragma unroll
    for (int off = 1; off < NN; off <<= 1) {
        const int a = (t >= off) ? sb[t - off] : 0;
        __syncthreads();
        sb[t] += a;
        __syncthreads();
    }
    const int excl = sb[t] - v;
    row_ptr[t] = excl;
    fill[t]    = excl;
    if (t == NN - 1) row_ptr[NN] = sb[t];
    const int bkt = v < 63 ? v : 63;
    atomicAdd(&hist[bkt], 1);
    __syncthreads();
    if (t == 0) {
        int s = 0;
        for (int q = 0; q < 64; ++q) { hoff[q] = s; s += hist[q]; }
    }
    __syncthreads();
    const int pos = atomicAdd(&hoff[bkt], 1);
    jorder[pos] = t;
}

__global__ __launch_bounds__(1024) void k_scatter(const int* __restrict__ erow,
                                                  const int* __restrict__ ecol,
                                                  int* __restrict__ fill,
                                                  int* __restrict__ cols, int n_edges) {
    const int e = blockIdx.x * 1024 + threadIdx.x;
    if (e < n_edges) {
        const int pos = atomicAdd(&fill[erow[e]], 1);
        cols[pos] = ecol[e];
    }
}

// ---------------- main: block per i ----------------
// LDS layout (bytes):
//   Xl        @0      : CAP*32 floats (71680), rows XOR-swizzled by (slot&7)
//   slot_map  @71680  : 1024 int16   (k -> slot; -2 masked-out, -1 overflow)
//   sk        @73728  : 576  int16   (slot -> k)
//   jl        @74880  : 1024 uint16  (compacted j list: [0,Rj) masked, rest unmasked)
//   scr       @76928  : ints wt[16] woff[16] wt2[16] woff2[16] Rj
#define SMEM_BYTES 77248

__global__ __launch_bounds__(1024, 8) void ngnn_main_kernel(
    const float* __restrict__ X, const int* __restrict__ mask,
    const float* __restrict__ W, const float* __restrict__ b,
    const int* __restrict__ row_ptr, const int* __restrict__ cols,
    const int* __restrict__ jorder,
    float* __restrict__ out)
{
    extern __shared__ float smem[];
    float*          Xl       = smem;
    short*          slot_map = (short*)((char*)smem + 71680);
    short*          sk       = (short*)((char*)smem + 73728);
    unsigned short* jl       = (unsigned short*)((char*)smem + 74880);
    int*            scr      = (int*)((char*)smem + 76928);
    int* wt    = scr;       // [16]
    int* woff  = scr + 16;  // [16]
    int* wt2   = scr + 32;  // [16]
    int* woff2 = scr + 48;  // [16]
    int* RjS   = scr + 64;

    const int t    = threadIdx.x;
    const int i    = blockIdx.x;
    const int w    = t >> 6;
    const int lane = t & 63;
    const unsigned long long ltmask = (lane == 63) ? 0x7fffffffffffffffull
                                                   : ((1ull << lane) - 1ull);

    // ---- phase 0a: per-wave scan of mask row -> compacted k slots ----
    const int mk = mask[(size_t)i * NN + t];
    const int jj = jorder[t];                    // for phase 0b
    const unsigned long long bal = __ballot(mk != 0);
    const int rank = __popcll(bal & ltmask);
    if (lane == 0) wt[w] = __popcll(bal);
    __syncthreads();
    if (t == 0) {
        int s = 0;
        #pragma unroll
        for (int q = 0; q < 16; ++q) { woff[q] = s; s += wt[q]; }
    }
    __syncthreads();
    int slot = -2;
    if (mk) { slot = woff[w] + rank; if (slot >= CAP) slot = -1; }
    slot_map[t] = (short)slot;
    if (slot >= 0) sk[slot] = (short)t;
    const int R = woff[15] + wt[15];
    __syncthreads();                             // slot_map/sk ready

    // ---- phase 0b: compact j's (in degree-sorted jorder) by mask ----
    const int mj = (slot_map[jj] != -2);
    const unsigned long long bal2 = __ballot(mj);
    const int rank2 = __popcll(bal2 & ltmask);
    if (lane == 0) wt2[w] = __popcll(bal2);
    __syncthreads();
    if (t == 0) {
        int s = 0;
        #pragma unroll
        for (int q = 0; q < 16; ++q) { woff2[q] = s; s += wt2[q]; }
        *RjS = s;
    }
    __syncthreads();
    const int Rj = *RjS;
    if (mj) jl[woff2[w] + rank2] = (unsigned short)jj;
    else    jl[Rj + (64 * w - woff2[w]) + (lane - rank2)] = (unsigned short)jj;

    // ---- phase 1: copy masked rows into LDS (coalesced-ish, swizzled) ----
    const int Rcap = R < CAP ? R : CAP;
    const float4* Xg4 = (const float4*)(X + (size_t)i * NN * IND);
    for (int idx = t; idx < Rcap * 8; idx += 1024) {
        const int s = idx >> 3, q = idx & 7;
        const int k = sk[s];
        const float4 v = Xg4[k * 8 + q];
        *(float4*)(Xl + s * IND + ((q ^ (s & 7)) << 2)) = v;
    }
    __syncthreads();                             // Xl + jl ready

    // ---- phase 2: aggregate ----
    const int jv = jl[t];
    float4* orow = (float4*)(out + ((size_t)i * NN + jv) * OUTD);

    if (t >= Rj) {                               // masked-out j: exact zeros
        const float4 z = {0.f, 0.f, 0.f, 0.f};
        #pragma unroll
        for (int q = 0; q < 8; ++q) orow[q] = z;
        return;
    }

    float S[IND];
    #pragma unroll
    for (int d = 0; d < IND; ++d) S[d] = 0.f;
    float cntf = 0.f;

    const int e0 = row_ptr[jv];
    const int e1 = row_ptr[jv + 1];
    for (int e = e0; e < e1; ++e) {
        const int k = cols[e];
        const int s = slot_map[k];
        if (s >= 0) {
            cntf += 1.f;
            const float* rb = Xl + s * IND;
            const int sx = (s & 7) << 2;
            #pragma unroll
            for (int q = 0; q < 8; ++q) {
                const float4 v = *(const float4*)(rb + ((q << 2) ^ sx));
                S[q * 4 + 0] += v.x; S[q * 4 + 1] += v.y;
                S[q * 4 + 2] += v.z; S[q * 4 + 3] += v.w;
            }
        } else if (s == -1) {                    // overflow fallback: global
            cntf += 1.f;
            const float4* xr = (const float4*)(X + ((size_t)i * NN + k) * IND);
            #pragma unroll
            for (int q = 0; q < 8; ++q) {
                const float4 v = xr[q];
                S[q * 4 + 0] += v.x; S[q * 4 + 1] += v.y;
                S[q * 4 + 2] += v.z; S[q * 4 + 3] += v.w;
            }
        }
    }

    // ---- phase 3: o = S @ W + b*cnt (W/b wave-uniform -> scalar loads) ----
    const float4* W4 = (const float4*)W;
    const float4* b4 = (const float4*)b;
    #pragma unroll
    for (int g = 0; g < 8; ++g) {
        const float4 bb = b4[g];
        float4 acc = { bb.x * cntf, bb.y * cntf, bb.z * cntf, bb.w * cntf };
        #pragma unroll
        for (int d = 0; d < IND; ++d) {
            const float4 wv = W4[d * 8 + g];
            const float s = S[d];
            acc.x += s * wv.x; acc.y += s * wv.y;
            acc.z += s * wv.z; acc.w += s * wv.w;
        }
        orow[g] = acc;
    }
}

extern "C" void kernel_launch(void* const* d_in, const int* in_sizes, int n_in,
                              void* d_out, int out_size, void* d_ws, size_t ws_size,
                              hipStream_t stream) {
    const float* X    = (const float*)d_in[0];
    const int*   mask = (const int*)d_in[1];
    const int*   erow = (const int*)d_in[2];
    const int*   ecol = (const int*)d_in[3];
    const float* W    = (const float*)d_in[4];
    const float* b    = (const float*)d_in[5];
    float*       out  = (float*)d_out;

    const int n_edges = in_sizes[2];

    // ws (ints): row_ptr[1025] @0 | cnt(=fill) @1088 | jorder @2112 | cols @3136
    int* row_ptr = (int*)d_ws;
    int* cnt     = row_ptr + 1088;
    int* jorder  = row_ptr + 2112;
    int* cols    = row_ptr + 3136;

    const int eb = (n_edges + 1023) / 1024;
    k_zero     <<<1, 1024, 0, stream>>>(cnt, NN);
    k_count    <<<eb, 1024, 0, stream>>>(erow, cnt, n_edges);
    k_scan_sort<<<1, 1024, 0, stream>>>(cnt, row_ptr, cnt /*fill alias*/, jorder);
    k_scatter  <<<eb, 1024, 0, stream>>>(erow, ecol, cnt, cols, n_edges);

    hipFuncSetAttribute((const void*)ngnn_main_kernel,
                        hipFuncAttributeMaxDynamicSharedMemorySize, SMEM_BYTES);
    ngnn_main_kernel<<<NN, 1024, SMEM_BYTES, stream>>>(X, mask, W, b,
                                                       row_ptr, cols, jorder, out);
}